// Round 16
// baseline (91.421 us; speedup 1.0000x reference)
//
#include <hip/hip_runtime.h>

#define N_TASKS 16
#define LMAX 64
#define TSTRIDE 136  // dwords per task row (A/B-neutral vs 128; kept)

typedef float f32x4 __attribute__((ext_vector_type(4)));

__global__ __launch_bounds__(256) void MultiElementWiseAffine_kernel(
    const float* __restrict__ input,      // [B]
    const int*   __restrict__ task_ids,   // [B]
    const float* __restrict__ offsets,    // [N_TASKS*LMAX]
    const float* __restrict__ disc,       // [N_TASKS*LMAX]
    const int*   __restrict__ lengths,    // [N_TASKS]
    f32x4*       __restrict__ out,        // [B*16] float4 view of [B][64]
    int total4)                           // B*16
{
    // Per-task: [t*136 + 0..63] = masked disc (m), [t*136 + 64..127] = m*offset.
    __shared__ alignas(16) float s_tab[N_TASKS * TSTRIDE];

    for (int i = threadIdx.x; i < N_TASKS * LMAX; i += blockDim.x) {
        int t = i >> 6;          // task
        int k = i & (LMAX - 1);  // threshold index
        float m = (k < lengths[t]) ? disc[i] : 0.0f;
        s_tab[t * TSTRIDE + k]      = m;
        s_tab[t * TSTRIDE + 64 + k] = m * offsets[i];
    }
    __syncthreads();

    const int stride = gridDim.x * blockDim.x;
    int g = blockIdx.x * blockDim.x + threadIdx.x;
    if (g >= total4) return;

    // Depth-1 pipeline (depth-2 was A/B-neutral, reverted to simpler form).
    int   t_cur = task_ids[g >> 4];
    float x_cur = input[g >> 4];

    for (; g < total4; g += stride) {
        int gn      = g + stride;
        int rown    = (gn < total4 ? gn : g) >> 4;
        int t_nxt   = task_ids[rown];
        float x_nxt = input[rown];

        int k4 = g & 15;
        const float* base = &s_tab[t_cur * TSTRIDE + (k4 << 2)];
        f32x4 mv = *(const f32x4*)(base);       // ds_read_b128
        f32x4 pv = *(const f32x4*)(base + 64);  // ds_read_b128 offset:256
        f32x4 r;
        r.x = fmaf(mv.x, x_cur, pv.x);
        r.y = fmaf(mv.y, x_cur, pv.y);
        r.z = fmaf(mv.z, x_cur, pv.z);
        r.w = fmaf(mv.w, x_cur, pv.w);
        // ONLY change vs R12: plain store (nt was A/B'd only at grid 2048,
        // where L2 thrash from 8192 streams may have been what plain lost to).
        out[g] = r;

        t_cur = t_nxt;
        x_cur = x_nxt;
    }
}

extern "C" void kernel_launch(void* const* d_in, const int* in_sizes, int n_in,
                              void* d_out, int out_size, void* d_ws, size_t ws_size,
                              hipStream_t stream) {
    const float* input    = (const float*)d_in[0];
    const int*   task_ids = (const int*)d_in[1];
    const float* offsets  = (const float*)d_in[2];
    const float* disc     = (const float*)d_in[3];
    const int*   lengths  = (const int*)d_in[4];
    f32x4*       out      = (f32x4*)d_out;

    int total4 = out_size / 4;           // B * 16
    int block  = 256;
    int grid   = 512;                    // R12-proven sweet spot (2 blocks/CU)

    MultiElementWiseAffine_kernel<<<grid, block, 0, stream>>>(
        input, task_ids, offsets, disc, lengths, out, total4);
}

// Round 17
// 53.991 us; speedup vs baseline: 1.6933x; 1.6933x over previous
//
#include <hip/hip_runtime.h>

#define N_TASKS 16
#define LMAX 64
#define TSTRIDE 136  // dwords per task row (A/B-neutral vs 128; kept)

typedef float f32x4 __attribute__((ext_vector_type(4)));

// Warm input+task_ids (8.4 MB total) into L2/Infinity Cache so the main
// kernel's gathers never touch HBM -> no read/write bus turnarounds during
// the store stream. asm keeps the loads live (rule: ablation-via-skip DCEs).
__global__ __launch_bounds__(256) void MEWA_prefetch(
    const f32x4* __restrict__ a, const f32x4* __restrict__ b, int n4)
{
    const int stride = gridDim.x * blockDim.x;
    float s = 0.0f;
    for (int i = blockIdx.x * blockDim.x + threadIdx.x; i < n4; i += stride) {
        f32x4 v = a[i];
        f32x4 w = b[i];
        s += v.x + w.x;
    }
    asm volatile("" :: "v"(s));
}

__global__ __launch_bounds__(256) void MultiElementWiseAffine_kernel(
    const float* __restrict__ input,      // [B]
    const int*   __restrict__ task_ids,   // [B]
    const float* __restrict__ offsets,    // [N_TASKS*LMAX]
    const float* __restrict__ disc,       // [N_TASKS*LMAX]
    const int*   __restrict__ lengths,    // [N_TASKS]
    f32x4*       __restrict__ out,        // [B*16] float4 view of [B][64]
    int total4)                           // B*16
{
    // Per-task: [t*136 + 0..63] = masked disc (m), [t*136 + 64..127] = m*offset.
    __shared__ alignas(16) float s_tab[N_TASKS * TSTRIDE];

    for (int i = threadIdx.x; i < N_TASKS * LMAX; i += blockDim.x) {
        int t = i >> 6;          // task
        int k = i & (LMAX - 1);  // threshold index
        float m = (k < lengths[t]) ? disc[i] : 0.0f;
        s_tab[t * TSTRIDE + k]      = m;
        s_tab[t * TSTRIDE + 64 + k] = m * offsets[i];
    }
    __syncthreads();

    const int stride = gridDim.x * blockDim.x;
    int g = blockIdx.x * blockDim.x + threadIdx.x;
    if (g >= total4) return;

    // Depth-1 pipeline; in-loop gathers (proven); now L3-resident via prefetch.
    int   t_cur = task_ids[g >> 4];
    float x_cur = input[g >> 4];

    for (; g < total4; g += stride) {
        int gn      = g + stride;
        int rown    = (gn < total4 ? gn : g) >> 4;
        int t_nxt   = task_ids[rown];
        float x_nxt = input[rown];

        int k4 = g & 15;
        const float* base = &s_tab[t_cur * TSTRIDE + (k4 << 2)];
        f32x4 mv = *(const f32x4*)(base);       // ds_read_b128
        f32x4 pv = *(const f32x4*)(base + 64);  // ds_read_b128 offset:256
        f32x4 r;
        r.x = fmaf(mv.x, x_cur, pv.x);
        r.y = fmaf(mv.y, x_cur, pv.y);
        r.z = fmaf(mv.z, x_cur, pv.z);
        r.w = fmaf(mv.w, x_cur, pv.w);
        // Lane-dense 1KB/wave, grid-stride walk, nt (all A/B-proven).
        __builtin_nontemporal_store(r, &out[g]);

        t_cur = t_nxt;
        x_cur = x_nxt;
    }
}

extern "C" void kernel_launch(void* const* d_in, const int* in_sizes, int n_in,
                              void* d_out, int out_size, void* d_ws, size_t ws_size,
                              hipStream_t stream) {
    const float* input    = (const float*)d_in[0];
    const int*   task_ids = (const int*)d_in[1];
    const float* offsets  = (const float*)d_in[2];
    const float* disc     = (const float*)d_in[3];
    const int*   lengths  = (const int*)d_in[4];
    f32x4*       out      = (f32x4*)d_out;

    int total4 = out_size / 4;           // B * 16
    int nB     = in_sizes[1];            // B (task_ids count)

    // Stage 1: warm the 8.4 MB of gather data into cache (~1.5 us).
    MEWA_prefetch<<<256, 256, 0, stream>>>(
        (const f32x4*)input, (const f32x4*)task_ids, nB / 4);

    // Stage 2: R12 champion, byte-identical (nt, grid 512, depth-1 pipeline).
    MultiElementWiseAffine_kernel<<<512, 256, 0, stream>>>(
        input, task_ids, offsets, disc, lengths, out, total4);
}

// Round 18
// 49.684 us; speedup vs baseline: 1.8401x; 1.0867x over previous
//
#include <hip/hip_runtime.h>

#define N_TASKS 16
#define LMAX 64
#define TSTRIDE 136  // dwords per task row (A/B-neutral vs 128; kept)

typedef float f32x4 __attribute__((ext_vector_type(4)));

__global__ __launch_bounds__(256) void MultiElementWiseAffine_kernel(
    const float* __restrict__ input,      // [B]
    const int*   __restrict__ task_ids,   // [B]
    const float* __restrict__ offsets,    // [N_TASKS*LMAX]
    const float* __restrict__ disc,       // [N_TASKS*LMAX]
    const int*   __restrict__ lengths,    // [N_TASKS]
    f32x4*       __restrict__ out,        // [B*16] float4 view of [B][64]
    int total4)                           // B*16
{
    // Per-task: [t*136 + 0..63] = masked disc (m), [t*136 + 64..127] = m*offset.
    __shared__ alignas(16) float s_tab[N_TASKS * TSTRIDE];

    for (int i = threadIdx.x; i < N_TASKS * LMAX; i += blockDim.x) {
        int t = i >> 6;          // task
        int k = i & (LMAX - 1);  // threshold index
        float m = (k < lengths[t]) ? disc[i] : 0.0f;
        s_tab[t * TSTRIDE + k]      = m;
        s_tab[t * TSTRIDE + 64 + k] = m * offsets[i];
    }
    __syncthreads();

    const int stride = gridDim.x * blockDim.x;
    int g = blockIdx.x * blockDim.x + threadIdx.x;
    if (g >= total4) return;

    // Depth-1 pipeline; in-loop gathers (proven best across 4 staging attempts).
    int   t_cur = task_ids[g >> 4];
    float x_cur = input[g >> 4];

    for (; g < total4; g += stride) {
        int gn      = g + stride;
        int rown    = (gn < total4 ? gn : g) >> 4;
        int t_nxt   = task_ids[rown];
        float x_nxt = input[rown];

        int k4 = g & 15;
        const float* base = &s_tab[t_cur * TSTRIDE + (k4 << 2)];
        f32x4 mv = *(const f32x4*)(base);       // ds_read_b128
        f32x4 pv = *(const f32x4*)(base + 64);  // ds_read_b128 offset:256
        f32x4 r;
        r.x = fmaf(mv.x, x_cur, pv.x);
        r.y = fmaf(mv.y, x_cur, pv.y);
        r.z = fmaf(mv.z, x_cur, pv.z);
        r.w = fmaf(mv.w, x_cur, pv.w);
        // Lane-dense 1KB/wave, grid-stride walk, nt (all A/B-proven).
        __builtin_nontemporal_store(r, &out[g]);

        t_cur = t_nxt;
        x_cur = x_nxt;
    }
}

extern "C" void kernel_launch(void* const* d_in, const int* in_sizes, int n_in,
                              void* d_out, int out_size, void* d_ws, size_t ws_size,
                              hipStream_t stream) {
    const float* input    = (const float*)d_in[0];
    const int*   task_ids = (const int*)d_in[1];
    const float* offsets  = (const float*)d_in[2];
    const float* disc     = (const float*)d_in[3];
    const int*   lengths  = (const int*)d_in[4];
    f32x4*       out      = (f32x4*)d_out;

    int total4 = out_size / 4;           // B * 16
    int block  = 256;
    // Final grid fine-sweep point: 2048->52.5us, 1024->?, 512->48.6, 256->157.
    int grid   = 1024;

    MultiElementWiseAffine_kernel<<<grid, block, 0, stream>>>(
        input, task_ids, offsets, disc, lengths, out, total4);
}

// Round 19
// 48.888 us; speedup vs baseline: 1.8700x; 1.0163x over previous
//
#include <hip/hip_runtime.h>

#define N_TASKS 16
#define LMAX 64
#define TSTRIDE 136  // dwords per task row (A/B-neutral vs 128; kept)

typedef float f32x4 __attribute__((ext_vector_type(4)));

// CHAMPION (R12): 48.6 us, 5.43 TB/s aggregate (86% of achievable-copy ceiling).
// A/B-proven ingredients:
//  - lane-dense stores: lane i -> base + i*16B, 1KB per wave store inst (R3: widening -> -31%)
//  - grid-stride output walk (R6: per-block slabs -> -19%)
//  - nt store (R10/R16: plain store -21%@2048, -47%@512)
//  - premultiplied table: r = m*x + (m*o), 2 ds_read_b128 from one base (R5: +7%)
//  - in-loop gathers, depth-1 pipeline (staging slower x4: R7/R9/R11/R14; depth-2 neutral)
//  - grid 512 = 2 blocks/CU (sweep: 2048->52.5, 1024->49.7, 512->48.6, 256->157)
__global__ __launch_bounds__(256) void MultiElementWiseAffine_kernel(
    const float* __restrict__ input,      // [B]
    const int*   __restrict__ task_ids,   // [B]
    const float* __restrict__ offsets,    // [N_TASKS*LMAX]
    const float* __restrict__ disc,       // [N_TASKS*LMAX]
    const int*   __restrict__ lengths,    // [N_TASKS]
    f32x4*       __restrict__ out,        // [B*16] float4 view of [B][64]
    int total4)                           // B*16
{
    // Per-task: [t*136 + 0..63] = masked disc (m), [t*136 + 64..127] = m*offset.
    __shared__ alignas(16) float s_tab[N_TASKS * TSTRIDE];

    for (int i = threadIdx.x; i < N_TASKS * LMAX; i += blockDim.x) {
        int t = i >> 6;          // task
        int k = i & (LMAX - 1);  // threshold index
        float m = (k < lengths[t]) ? disc[i] : 0.0f;
        s_tab[t * TSTRIDE + k]      = m;
        s_tab[t * TSTRIDE + 64 + k] = m * offsets[i];
    }
    __syncthreads();

    const int stride = gridDim.x * blockDim.x;
    int g = blockIdx.x * blockDim.x + threadIdx.x;
    if (g >= total4) return;

    // Depth-1 pipeline: next iteration's row data prefetched -> table ds_reads
    // issue at loop top (single LDS hop per iteration).
    int   t_cur = task_ids[g >> 4];
    float x_cur = input[g >> 4];

    for (; g < total4; g += stride) {
        int gn      = g + stride;
        int rown    = (gn < total4 ? gn : g) >> 4;
        int t_nxt   = task_ids[rown];
        float x_nxt = input[rown];

        int k4 = g & 15;
        const float* base = &s_tab[t_cur * TSTRIDE + (k4 << 2)];
        f32x4 mv = *(const f32x4*)(base);       // ds_read_b128
        f32x4 pv = *(const f32x4*)(base + 64);  // ds_read_b128 offset:256
        f32x4 r;
        r.x = fmaf(mv.x, x_cur, pv.x);
        r.y = fmaf(mv.y, x_cur, pv.y);
        r.z = fmaf(mv.z, x_cur, pv.z);
        r.w = fmaf(mv.w, x_cur, pv.w);
        __builtin_nontemporal_store(r, &out[g]);

        t_cur = t_nxt;
        x_cur = x_nxt;
    }
}

extern "C" void kernel_launch(void* const* d_in, const int* in_sizes, int n_in,
                              void* d_out, int out_size, void* d_ws, size_t ws_size,
                              hipStream_t stream) {
    const float* input    = (const float*)d_in[0];
    const int*   task_ids = (const int*)d_in[1];
    const float* offsets  = (const float*)d_in[2];
    const float* disc     = (const float*)d_in[3];
    const int*   lengths  = (const int*)d_in[4];
    f32x4*       out      = (f32x4*)d_out;

    int total4 = out_size / 4;           // B * 16
    int block  = 256;
    int grid   = 512;                    // sweep-proven optimum (2 blocks/CU)

    MultiElementWiseAffine_kernel<<<grid, block, 0, stream>>>(
        input, task_ids, offsets, disc, lengths, out, total4);
}